// Round 3
// baseline (183.130 us; speedup 1.0000x reference)
//
#include <hip/hip_runtime.h>
#include <hip/hip_bf16.h>

typedef __bf16 bf16x8 __attribute__((ext_vector_type(8)));
typedef float f32x4 __attribute__((ext_vector_type(4)));
typedef float f32x16 __attribute__((ext_vector_type(16)));
typedef int int4v __attribute__((ext_vector_type(4)));
typedef unsigned int uint4v __attribute__((ext_vector_type(4)));
typedef unsigned short u16x8 __attribute__((ext_vector_type(8)));

#define N_NODES 8192
#define D_FEAT 128

// ---------------------------------------------------------------------------
// Bit->bf16 pair unpack: byte (8 adjacency bits) -> bf16x8 of {0.0, 1.0}.
// All muls fit u24 operand range (v_mul_u32_u24, full rate).
__device__ __forceinline__ bf16x8 unpack_byte(unsigned dword, int sh) {
  unsigned P = ((dword >> sh) & 0xFFu) * 0x8001u;
  uint4v c;
  c[0] = (P & 0x10001u) * 0x3F80u;
  c[1] = ((P >> 2) & 0x10001u) * 0x3F80u;
  c[2] = ((P >> 4) & 0x10001u) * 0x3F80u;
  c[3] = ((P >> 6) & 0x10001u) * 0x3F80u;
  return __builtin_bit_cast(bf16x8, c);
}

// ---------------------------------------------------------------------------
// Bpk fragment build (verified round-2). Fragment f = kk*256 + ng*64 + l
// holds, at element e: F[sigma(kk*16 + (l>>5)*8 + e)][ng*32 + (l&31)],
// sigma(p) = 256*(p>>8) + 32*((p>>3)&7) + 4*(p&7) + ((p>>6)&3).
__device__ __forceinline__ void bpk32_store(const float* __restrict__ src,
                                            unsigned short* __restrict__ Bpk,
                                            int W) {
  const int kk = W >> 8;
  const int ng = (W >> 6) & 3;
  const int l = W & 63;
  const int d = ng * 32 + (l & 31);
  const int p0 = kk * 16 + (l >> 5) * 8;
  const int n0 = (p0 >> 8) * 256 + ((p0 >> 3) & 7) * 32 + ((p0 >> 6) & 3);
  u16x8 pk;
#pragma unroll
  for (int e = 0; e < 8; ++e) {
    __bf16 v = (__bf16)src[(long)(n0 + 4 * e) * D_FEAT + d];
    pk[e] = __builtin_bit_cast(unsigned short, v);
  }
  *(u16x8*)(Bpk + (long)W * 8) = pk;
}

// ---------------------------------------------------------------------------
// K1: persistent pack. Blocks 0..511: layer-1 Bpk build (short, run first).
// Blocks 512..2559: persistent (8 rows each, stride 2048) ballot-pack of
// BOTH layers' adjacency with nontemporal streaming loads.
__global__ __launch_bounds__(256) void pack_all_kernel(
    const int* __restrict__ adj, unsigned long long* __restrict__ bits64,
    int* __restrict__ deg, const float* __restrict__ fsrc,
    unsigned short* __restrict__ Bpk) {
  const int bx = blockIdx.x;
  const int t = threadIdx.x;

  if (bx < 512) {  // layer-1 Bpk build
    bpk32_store(fsrc, Bpk, bx * 256 + t);
    return;
  }

  const int bxp = bx - 512;  // 0..2047
  const int w = t >> 6;
  const int lane = t & 63;
  __shared__ int red[2][4];

  for (int it = 0; it < 8; ++it) {
    const int row = bxp + it * 2048;  // 0..16383 over both layers
    const int4v* p = (const int4v*)(adj + ((long)row << 13));
    int4v v[8];
#pragma unroll
    for (int j = 0; j < 8; ++j)
      v[j] = __builtin_nontemporal_load(p + j * 256 + t);

    unsigned long long* brow = bits64 + ((long)row << 7);
    int cnt = 0;
#pragma unroll
    for (int j = 0; j < 8; ++j) {
      unsigned long long b0 = __ballot(v[j][0] != 0);
      unsigned long long b1 = __ballot(v[j][1] != 0);
      unsigned long long b2 = __ballot(v[j][2] != 0);
      unsigned long long b3 = __ballot(v[j][3] != 0);
      cnt += __popcll(b0) + __popcll(b1) + __popcll(b2) + __popcll(b3);
      unsigned long long bsel = b0;
      if (lane == 1) bsel = b1;
      if (lane == 2) bsel = b2;
      if (lane == 3) bsel = b3;
      if (lane < 4) brow[16 * j + 4 * w + lane] = bsel;
    }
    if (lane == 0) red[it & 1][w] = cnt;
    __syncthreads();
    if (t == 0)
      deg[row] =
          red[it & 1][0] + red[it & 1][1] + red[it & 1][2] + red[it & 1][3];
    // double-buffered red -> one barrier per iteration is sufficient
  }
}

// ---------------------------------------------------------------------------
// K3: rebuild Bpk from layer-1 output.
__global__ __launch_bounds__(256) void bpk_build32_kernel(
    const float* __restrict__ src, unsigned short* __restrict__ Bpk) {
  bpk32_store(src, Bpk, blockIdx.x * 256 + threadIdx.x);
}

// ---------------------------------------------------------------------------
// Split-K combine helpers (shufflevector needs literal indices).
__device__ __forceinline__ void st_acc(f32x4 (*red)[16][64], int slot, int A,
                                       int lane, f32x16 v) {
  red[slot][A * 4 + 0][lane] = __builtin_shufflevector(v, v, 0, 1, 2, 3);
  red[slot][A * 4 + 1][lane] = __builtin_shufflevector(v, v, 4, 5, 6, 7);
  red[slot][A * 4 + 2][lane] = __builtin_shufflevector(v, v, 8, 9, 10, 11);
  red[slot][A * 4 + 3][lane] = __builtin_shufflevector(v, v, 12, 13, 14, 15);
}
__device__ __forceinline__ void ld_acc(f32x4 (*red)[16][64], int slot, int A,
                                       int lane, f32x16* v) {
#pragma unroll
  for (int c = 0; c < 4; ++c) {
    f32x4 r = red[slot][A * 4 + c][lane];
    (*v)[4 * c + 0] += r[0];
    (*v)[4 * c + 1] += r[1];
    (*v)[4 * c + 2] += r[2];
    (*v)[4 * c + 3] += r[3];
  }
}

// ---------------------------------------------------------------------------
// Layer body, 32x32x16 MFMA, both-share geometry.
// Block = 64 rows x 64 cols; 512 thr = 8 waves = 8 K-eighths (1024 bits each).
// Per wave: 2 m-tiles x 2 ng col-groups -> per s-step 2 unpacks + 2 B loads
// feed 4 independent MFMA chains (VALU/MFMA ~14 cyc, B traffic 256 MiB/layer).
// Index map (verified round-2, re-parametrized): bit offset of (kk,lh) =
// 16*kk + 8*lh with kk = 64*kh + 8*kg + s; dword = a[s>>1], sh = 8*lh+16*(s&1).
// C/D (m101): col = l&31, row = (r&3) + 8*(r>>2) + 4*(l>>5).
__device__ __forceinline__ void layer_body32(
    int rowblk, int nthalf,
    const unsigned* __restrict__ bits, const int* __restrict__ deg,
    const unsigned short* __restrict__ Bpk,
    const float* fin, float* fout,
    f32x4 (*red)[16][64]) {
  const int tid = threadIdx.x;
  const int lane = tid & 63;
  const int w = tid >> 6;        // kh eighth 0..7
  const int l31 = lane & 31;
  const int lh = lane >> 5;
  const int m0 = rowblk * 64;
  const int ng0 = nthalf * 2;    // global col-groups ng0, ng0+1
  const int shA = lh * 8;

  // A: row stride 1 KiB = 64 uint4; eighth = 8 uint4.
  const uint4v* ap0 = (const uint4v*)(bits + ((long)(m0 + l31) << 8)) + w * 8;
  const uint4v* ap1 =
      (const uint4v*)(bits + ((long)(m0 + 32 + l31) << 8)) + w * 8;
  // B: fragment f = kk*256 + ng*64 + lane; eighth base = 64*kh*256 = kh<<14.
  const bf16x8* bp = (const bf16x8*)Bpk + ((long)w << 14) + ng0 * 64 + lane;

  f32x16 acc00 = {0.f, 0.f, 0.f, 0.f, 0.f, 0.f, 0.f, 0.f,
                  0.f, 0.f, 0.f, 0.f, 0.f, 0.f, 0.f, 0.f};
  f32x16 acc01 = acc00, acc10 = acc00, acc11 = acc00;

#pragma unroll 2
  for (int kg = 0; kg < 8; ++kg) {
    uint4v a0 = ap0[kg];
    uint4v a1 = ap1[kg];
#pragma unroll
    for (int s = 0; s < 8; ++s) {
      bf16x8 bv0 = bp[0];
      bf16x8 bv1 = bp[64];
      bp += 256;  // next kk
      const int sh = shA + (s & 1) * 16;
      bf16x8 af0 = unpack_byte(a0[s >> 1], sh);
      bf16x8 af1 = unpack_byte(a1[s >> 1], sh);
      acc00 = __builtin_amdgcn_mfma_f32_32x32x16_bf16(af0, bv0, acc00, 0, 0, 0);
      acc10 = __builtin_amdgcn_mfma_f32_32x32x16_bf16(af1, bv0, acc10, 0, 0, 0);
      acc01 = __builtin_amdgcn_mfma_f32_32x32x16_bf16(af0, bv1, acc01, 0, 0, 0);
      acc11 = __builtin_amdgcn_mfma_f32_32x32x16_bf16(af1, bv1, acc11, 0, 0, 0);
    }
  }

  // Two-phase 8-way split-K combine in 64 KiB LDS.
  if (w >= 4) {
    st_acc(red, w - 4, 0, lane, acc00);
    st_acc(red, w - 4, 1, lane, acc01);
    st_acc(red, w - 4, 2, lane, acc10);
    st_acc(red, w - 4, 3, lane, acc11);
  }
  __syncthreads();
  if (w < 4) {
    ld_acc(red, w, 0, lane, &acc00);
    ld_acc(red, w, 1, lane, &acc01);
    ld_acc(red, w, 2, lane, &acc10);
    ld_acc(red, w, 3, lane, &acc11);
  }
  __syncthreads();  // all waves 0..3 done reading their slot
  if (w >= 1 && w < 4) {
    st_acc(red, w, 0, lane, acc00);
    st_acc(red, w, 1, lane, acc01);
    st_acc(red, w, 2, lane, acc10);
    st_acc(red, w, 3, lane, acc11);
  }
  __syncthreads();
  if (w != 0) return;
#pragma unroll
  for (int q = 1; q < 4; ++q) {
    ld_acc(red, q, 0, lane, &acc00);
    ld_acc(red, q, 1, lane, &acc01);
    ld_acc(red, q, 2, lane, &acc10);
    ld_acc(red, q, 3, lane, &acc11);
  }

  // Epilogue (wave 0): col = ng*32 + l31, row = m0 + mt*32 + (r&3)+8*(r>>2)+4*lh.
#pragma unroll
  for (int mt = 0; mt < 2; ++mt) {
#pragma unroll
    for (int nn = 0; nn < 2; ++nn) {
#pragma unroll
      for (int r = 0; r < 16; ++r) {
        const int row = m0 + mt * 32 + (r & 3) + 8 * (r >> 2) + 4 * lh;
        const int dg = deg[row];
        float a;
        if (mt == 0 && nn == 0) a = acc00[r];
        else if (mt == 0 && nn == 1) a = acc01[r];
        else if (mt == 1 && nn == 0) a = acc10[r];
        else a = acc11[r];
        const long off = (long)row * D_FEAT + (ng0 + nn) * 32 + l31;
        fout[off] = dg > 0 ? a * (1.0f / (float)dg) : fin[off];
      }
    }
  }
}

// ---------------------------------------------------------------------------
// K2/K4: standalone layer GEMM. grid 256 = 128 rowblks x 2 col-halves.
__global__ __launch_bounds__(512, 2) void layer32_kernel(
    const unsigned* __restrict__ bits, const int* __restrict__ deg,
    const unsigned short* __restrict__ Bpk, const float* fin, float* fout) {
  __shared__ __align__(16) f32x4 red[4][16][64];  // 64 KiB
  layer_body32(blockIdx.x >> 1, blockIdx.x & 1, bits, deg, Bpk, fin, fout,
               red);
}

// ---------------------------------------------------------------------------
// Fallback path (round-1 verified), used only if ws too small.
__global__ __launch_bounds__(256) void transpose_cast_kernel(
    const float* __restrict__ src, unsigned short* __restrict__ dst) {
  __shared__ float tile[64][129];
  const int t = threadIdx.x;
  const int nbase = blockIdx.x * 64;
#pragma unroll
  for (int i = 0; i < 32; ++i) {
    int idx = t + i * 256;
    int nl = idx >> 7;
    int d = idx & 127;
    tile[nl][d] = src[(long)(nbase + nl) * D_FEAT + d];
  }
  __syncthreads();
#pragma unroll
  for (int i = 0; i < 32; ++i) {
    int idx = t + i * 256;
    int d = idx >> 6;
    int nl = idx & 63;
    __bf16 b = (__bf16)tile[nl][d];
    dst[(long)d * N_NODES + nbase + nl] = __builtin_bit_cast(unsigned short, b);
  }
}

__global__ __launch_bounds__(512) void layer_kernel_direct(
    const int* __restrict__ adj, const unsigned short* __restrict__ BT,
    const float* __restrict__ fin, float* __restrict__ fout) {
  const int tid = threadIdx.x;
  const int lane = tid & 63;
  const int w = tid >> 6;
  const int m0 = blockIdx.x * 32 + (w >> 2) * 16;
  const int n0 = (w & 3) * 32;
  const int lr = lane & 15;
  const int kc = lane >> 4;

  const int4v* ap = (const int4v*)(adj + (long)(m0 + lr) * N_NODES + kc * 8);
  const bf16x8* bp0 = (const bf16x8*)(BT + (long)(n0 + lr) * N_NODES + kc * 8);
  const bf16x8* bp1 =
      (const bf16x8*)(BT + (long)(n0 + 16 + lr) * N_NODES + kc * 8);

  f32x4 acc0 = {0.f, 0.f, 0.f, 0.f};
  f32x4 acc1 = {0.f, 0.f, 0.f, 0.f};
  int degv = 0;

#pragma unroll 4
  for (int k = 0; k < N_NODES; k += 32) {
    int4v alo = ap[0];
    int4v ahi = ap[1];
    bf16x8 b0 = bp0[0];
    bf16x8 b1 = bp1[0];
    ap += 8;
    bp0 += 4;
    bp1 += 4;
    unsigned short u[8];
    u[0] = alo[0] ? 0x3F80 : 0;
    u[1] = alo[1] ? 0x3F80 : 0;
    u[2] = alo[2] ? 0x3F80 : 0;
    u[3] = alo[3] ? 0x3F80 : 0;
    u[4] = ahi[0] ? 0x3F80 : 0;
    u[5] = ahi[1] ? 0x3F80 : 0;
    u[6] = ahi[2] ? 0x3F80 : 0;
    u[7] = ahi[3] ? 0x3F80 : 0;
    degv += alo[0] + alo[1] + alo[2] + alo[3] + ahi[0] + ahi[1] + ahi[2] +
            ahi[3];
    bf16x8 a;
    memcpy(&a, u, 16);
    acc0 = __builtin_amdgcn_mfma_f32_16x16x32_bf16(a, b0, acc0, 0, 0, 0);
    acc1 = __builtin_amdgcn_mfma_f32_16x16x32_bf16(a, b1, acc1, 0, 0, 0);
  }

  degv += __shfl_xor(degv, 16);
  degv += __shfl_xor(degv, 32);
  int dgv[4];
#pragma unroll
  for (int j = 0; j < 4; ++j) dgv[j] = __shfl(degv, kc * 4 + j);

#pragma unroll
  for (int t = 0; t < 2; ++t) {
    const f32x4 acc = t ? acc1 : acc0;
    const int col = n0 + t * 16 + lr;
#pragma unroll
    for (int j = 0; j < 4; ++j) {
      const long off = (long)(m0 + kc * 4 + j) * D_FEAT + col;
      fout[off] = dgv[j] > 0 ? acc[j] * (1.0f / (float)dgv[j]) : fin[off];
    }
  }
}

// ---------------------------------------------------------------------------
extern "C" void kernel_launch(void* const* d_in, const int* in_sizes, int n_in,
                              void* d_out, int out_size, void* d_ws,
                              size_t ws_size, hipStream_t stream) {
  const float* features = (const float*)d_in[0];
  const int* adj = (const int*)d_in[1];
  float* out = (float*)d_out;
  const long NN = (long)N_NODES * N_NODES;

  const size_t BITS_BYTES = 2ul * N_NODES * 128 * 8;      // 16 MiB
  const size_t BPK_BYTES = (size_t)D_FEAT * N_NODES * 2;  // 2 MiB
  const size_t NEED = BITS_BYTES + 65536 + BPK_BYTES;

  if (ws_size >= NEED) {
    unsigned long long* bits64 = (unsigned long long*)d_ws;
    int* degw = (int*)((char*)d_ws + BITS_BYTES);
    unsigned short* Bpk = (unsigned short*)((char*)d_ws + BITS_BYTES + 65536);
    const unsigned* bits32 = (const unsigned*)d_ws;

    // K1: persistent pack of both layers + layer-1 Bpk build.
    pack_all_kernel<<<2048 + 512, 256, 0, stream>>>(adj, bits64, degw,
                                                    features, Bpk);
    // K2: layer-1 GEMM (32x32x16, both-share, split-K8).
    layer32_kernel<<<256, 512, 0, stream>>>(bits32, degw, Bpk, features, out);
    // K3: rebuild Bpk from layer-1 output.
    bpk_build32_kernel<<<512, 256, 0, stream>>>(out, Bpk);
    // K4: layer-2 GEMM.
    layer32_kernel<<<256, 512, 0, stream>>>(bits32 + (size_t)N_NODES * 256,
                                            degw + N_NODES, Bpk, out, out);
  } else {
    // Fallback: round-1 verified path (needs only 2 MiB ws)
    unsigned short* BTw = (unsigned short*)d_ws;
    transpose_cast_kernel<<<N_NODES / 64, 256, 0, stream>>>(features, BTw);
    layer_kernel_direct<<<N_NODES / 32, 512, 0, stream>>>(adj, BTw, features,
                                                          out);
    transpose_cast_kernel<<<N_NODES / 64, 256, 0, stream>>>(out, BTw);
    layer_kernel_direct<<<N_NODES / 32, 512, 0, stream>>>(adj + NN, BTw, out,
                                                          out);
  }
}